// Round 6
// baseline (27.594 us; speedup 1.0000x reference)
//
#include <hip/hip_runtime.h>

// NeighborsConvolution: out[z,a,i] = sum_{b,x,j} [|r_b-r_a|<0.5] * (r_b-r_a)_x * W[x,i,j] * feat[z,b,j]
// B=8, N=1024, CIN=COUT=64.
//
// R6 vs R5 (latency-bound via barrier-coupled wave variance, NOT LDS-throughput):
//  - ZERO __syncthreads: scan reads geometry straight from global (L1-resident
//    12KB/batch), each wave runs a private full epilogue (48 coalesced Wt
//    float4 loads + 48 uniform b128 tmp broadcasts). Waves fully independent.
//  - Scan restored to conflict-free layout (R5's b128 scan was 8-way
//    bank-conflicted: byte stride 48 -> bank=(lane*12)%32, 8 banks).
//  - LDS 7KB/block (list CAP=64 b128 + tmp), 256-thread blocks,
//    __launch_bounds__(256,8), epilogue chunked (4 groups) for <=64 VGPR.

#define BATCHSZ 8
#define NPTS 1024
#define CIN 64
#define COUT 64
#define NG 48           // float4 groups of xj (192/4)
#define WPB 4           // waves (points) per block
#define BS (WPB * 64)   // 256
#define CAP 64          // per-wave neighbor list capacity (max expected ~30)

typedef float f32x2 __attribute__((ext_vector_type(2)));

__global__ __launch_bounds__(256) void transpose_W_kernel(
    const float* __restrict__ W,   // [3][COUT][CIN]
    float* __restrict__ Wt)        // [NG][COUT][4]
{
    const int t = blockIdx.x * 256 + threadIdx.x;
    if (t >= 3 * COUT * CIN) return;
    const int x = t >> 12;
    const int i = (t >> 6) & 63;
    const int j = t & 63;
    const int xj = x * CIN + j;
    Wt[((xj >> 2) * COUT + i) * 4 + (xj & 3)] = W[t];
}

template <bool WT>
__global__ __launch_bounds__(BS, 8) void neigh_conv_kernel(
    const float* __restrict__ feat,  // [B,N,CIN]
    const float* __restrict__ geom,  // [B,N,3]
    const float* __restrict__ Wv,    // WT ? Wt[NG][64][4] : W[3][64][64]
    float* __restrict__ out)         // [B,N,COUT]
{
    const int lane = threadIdx.x & 63;
    const int wv   = threadIdx.x >> 6;
    const int p    = blockIdx.x * WPB + wv;
    const int a    = p & (NPTS - 1);
    const int z    = p >> 10;

    __shared__ __align__(16) float4 list[WPB][CAP];      // 4 KB
    __shared__ __align__(16) float  tmp[WPB][3 * CIN];   // 3 KB

    const float* gz = geom + (size_t)z * NPTS * 3;
    const float* fz = feat + (size_t)z * NPTS * CIN;
    const float gax = gz[a * 3 + 0];
    const float gay = gz[a * 3 + 1];
    const float gaz = gz[a * 3 + 2];

    float4* list4 = list[wv];
    const unsigned long long ltmask = (1ull << lane) - 1ull;

    f32x2 axy = {0.f, 0.f};
    float az2 = 0.f;
    int nn = 0;

    // ---- scan: global geometry reads (L1-resident), ballot + compact ----
    #pragma unroll 4
    for (int bb = 0; bb < NPTS; bb += 64) {
        const int b = bb + lane;
        const float* gp = gz + (size_t)b * 3;
        float dx, dy, dz, d2;
        {
            // Bit-exact vs numpy near boundary: no contraction, left-assoc adds.
            #pragma clang fp contract(off)
            dx = gp[0] - gax;
            dy = gp[1] - gay;
            dz = gp[2] - gaz;
            d2 = dx * dx + dy * dy + dz * dz;
        }
        const bool hit = d2 < 0.25f;
        const unsigned long long m = __ballot(hit);
        const int c = __popcll(m);
        if (nn + c <= CAP) {               // wave-uniform branch
            if (hit) {
                const int slot = nn + __popcll(m & ltmask);
                float4 e;
                e.x = dx; e.y = dy; e.z = dz; e.w = __int_as_float(b);
                list4[slot] = e;
            }
            nn += c;
        } else {
            // overflow fallback (statistically never: CAP=64 vs max ~30)
            unsigned long long mm = m;
            while (mm) {
                const int src = __ffsll(mm) - 1;
                mm &= mm - 1ull;
                const float ddx = __shfl(dx, src);
                const float ddy = __shfl(dy, src);
                const float ddz = __shfl(dz, src);
                const float f = fz[(size_t)(bb + src) * CIN + lane];
                axy.x = fmaf(ddx, f, axy.x);
                axy.y = fmaf(ddy, f, axy.y);
                az2   = fmaf(ddz, f, az2);
            }
        }
    }

    // pad to multiple of 4 with null records (b=a -> diff 0, contributes 0)
    {
        const int npad = (4 - (nn & 3)) & 3;
        if (lane < npad) {
            float4 e;
            e.x = 0.f; e.y = 0.f; e.z = 0.f; e.w = __int_as_float(a);
            list4[nn + lane] = e;
        }
        nn += npad;
    }

    // ---- process neighbors 4 at a time (independent coalesced feat loads) ----
    for (int k = 0; k < nn; k += 4) {
        const float4 e0 = list4[k + 0];
        const float4 e1 = list4[k + 1];
        const float4 e2 = list4[k + 2];
        const float4 e3 = list4[k + 3];
        const float f0 = fz[(size_t)__float_as_int(e0.w) * CIN + lane];
        const float f1 = fz[(size_t)__float_as_int(e1.w) * CIN + lane];
        const float f2 = fz[(size_t)__float_as_int(e2.w) * CIN + lane];
        const float f3 = fz[(size_t)__float_as_int(e3.w) * CIN + lane];
        f32x2 d0; d0.x = e0.x; d0.y = e0.y;
        f32x2 d1; d1.x = e1.x; d1.y = e1.y;
        f32x2 d2; d2.x = e2.x; d2.y = e2.y;
        f32x2 d3; d3.x = e3.x; d3.y = e3.y;
        f32x2 ff0 = {f0, f0}, ff1 = {f1, f1}, ff2 = {f2, f2}, ff3 = {f3, f3};
        axy = d0 * ff0 + axy;  az2 = fmaf(e0.z, f0, az2);
        axy = d1 * ff1 + axy;  az2 = fmaf(e1.z, f1, az2);
        axy = d2 * ff2 + axy;  az2 = fmaf(e2.z, f2, az2);
        axy = d3 * ff3 + axy;  az2 = fmaf(e3.z, f3, az2);
    }

    // ---- per-wave tmp (no cross-wave sharing -> no barrier) ----
    float* tw = tmp[wv];
    tw[0 * CIN + lane] = axy.x;   // stride-1 across lanes: conflict-free
    tw[1 * CIN + lane] = axy.y;
    tw[2 * CIN + lane] = az2;

    // ---- private full epilogue: out[i=lane] = sum_g t[g] . Wt[g][lane] ----
    const float4* t4 = (const float4*)tw;     // uniform addr -> LDS broadcast
    f32x2 facc = {0.f, 0.f};
    if (WT) {
        const float4* w4 = (const float4*)Wv;
        #pragma unroll 4
        for (int g = 0; g < NG; ++g) {        // chunked by unroll: low VGPR
            const float4 t = t4[g];
            const float4 w = w4[g * COUT + lane];   // coalesced 1KB/instr, L2
            f32x2 ta; ta.x = t.x; ta.y = t.y;
            f32x2 tb; tb.x = t.z; tb.y = t.w;
            f32x2 wa; wa.x = w.x; wa.y = w.y;
            f32x2 wb; wb.x = w.z; wb.y = w.w;
            facc = ta * wa + facc;            // v_pk_fma_f32
            facc = tb * wb + facc;
        }
    } else {
        // fallback if ws too small: strided W reads (slow but correct)
        #pragma unroll 4
        for (int g = 0; g < NG; ++g) {
            const float4 t = t4[g];
            const int xj = 4 * g;
            float w0 = Wv[((xj + 0) >> 6) * 4096 + lane * 64 + ((xj + 0) & 63)];
            float w1 = Wv[((xj + 1) >> 6) * 4096 + lane * 64 + ((xj + 1) & 63)];
            float w2 = Wv[((xj + 2) >> 6) * 4096 + lane * 64 + ((xj + 2) & 63)];
            float w3 = Wv[((xj + 3) >> 6) * 4096 + lane * 64 + ((xj + 3) & 63)];
            facc.x = fmaf(t.x, w0, facc.x);
            facc.y = fmaf(t.y, w1, facc.y);
            facc.x = fmaf(t.z, w2, facc.x);
            facc.y = fmaf(t.w, w3, facc.y);
        }
    }

    out[(size_t)p * COUT + lane] = facc.x + facc.y;
}

extern "C" void kernel_launch(void* const* d_in, const int* in_sizes, int n_in,
                              void* d_out, int out_size, void* d_ws, size_t ws_size,
                              hipStream_t stream) {
    const float* feat = (const float*)d_in[0];  // [8,1024,64]
    const float* geom = (const float*)d_in[1];  // [8,1024,3]
    const float* W    = (const float*)d_in[2];  // [3,64,64]
    float* out        = (float*)d_out;          // [8,1024,64]

    const int nblocks = BATCHSZ * NPTS / WPB;   // 2048 blocks x 256 threads

    if (ws_size >= (size_t)(3 * COUT * CIN) * sizeof(float)) {
        float* Wt = (float*)d_ws;
        transpose_W_kernel<<<(3 * COUT * CIN + 255) / 256, 256, 0, stream>>>(W, Wt);
        neigh_conv_kernel<true><<<nblocks, BS, 0, stream>>>(feat, geom, Wt, out);
    } else {
        neigh_conv_kernel<false><<<nblocks, BS, 0, stream>>>(feat, geom, W, out);
    }
}

// Round 7
// 22.332 us; speedup vs baseline: 1.2356x; 1.2356x over previous
//
#include <hip/hip_runtime.h>

// NeighborsConvolution: out[z,a,i] = sum_{b,x,j} [|r_b-r_a|<0.5] * (r_b-r_a)_x * W[x,i,j] * feat[z,b,j]
// B=8, N=1024, CIN=COUT=64.
//
// R7 vs R4 (list write/read chains + nn-prefix serialization were the residual):
//  - MASK-SCAN: ballot masks for all 16 steps kept in wave-uniform SGPRs
//    (fully unrolled static array). No LDS list, no compact, no pad, no CAP.
//  - Process walks masks with scalar ffsll; b is wave-uniform -> geo re-read
//    is an LDS broadcast, diff recomputed bit-identically, feat load address
//    is SGPR-base + lane-offset. Neighbor loads issue-independent (pipelined).
//  - Wt fragment (6 float4/wave) prefetched at kernel top: L2 latency hides
//    under scan (T14 issue-early).
//  - Keeps R4's xj-split epilogue (W read 6KB/wave, 49MB aggregate) + LDS geo.

#define BATCHSZ 8
#define NPTS 1024
#define CIN 64
#define COUT 64
#define NXJ (3 * CIN)   // 192
#define NG (NXJ / 4)    // 48 float4 groups
#define PPB 8           // points (waves) per block
#define BS (PPB * 64)   // 512
#define GPW (NG / PPB)  // 6 W-groups per wave
#define NSTEP (NPTS / 64)  // 16 ballot steps

typedef float f32x2 __attribute__((ext_vector_type(2)));

// smem layout (floats):
//  [0,3072)     geo (12KB)            live: stage -> end of process
//  [3072,7168)  red[8][8][64] (16KB)  live: epilogue (after tmp barrier)
//  [7168,8704)  tmp[8][192] (6KB)
#define SM_RED 3072
#define SM_TMP 7168
#define SM_TOTAL 8704

__global__ __launch_bounds__(256) void transpose_W_kernel(
    const float* __restrict__ W,   // [3][COUT][CIN]
    float* __restrict__ Wt)        // [NG][COUT][4]
{
    const int t = blockIdx.x * 256 + threadIdx.x;
    if (t >= 3 * COUT * CIN) return;
    const int x = t >> 12;
    const int i = (t >> 6) & 63;
    const int j = t & 63;
    const int xj = x * CIN + j;
    Wt[((xj >> 2) * COUT + i) * 4 + (xj & 3)] = W[t];
}

template <bool WT>
__global__ __launch_bounds__(BS, 8) void neigh_conv_kernel(
    const float* __restrict__ feat,  // [B,N,CIN]
    const float* __restrict__ geom,  // [B,N,3]
    const float* __restrict__ Wv,    // WT ? Wt[NG][64][4] : W[3][64][64]
    float* __restrict__ out)         // [B,N,COUT]
{
    const int lane = threadIdx.x & 63;
    const int wv   = threadIdx.x >> 6;
    const int p    = blockIdx.x * PPB + wv;
    const int a    = p & (NPTS - 1);
    const int z    = p >> 10;        // uniform across block (8 | 1024)

    __shared__ __align__(16) float smem[SM_TOTAL];

    // ---- prefetch this wave's W fragment FIRST: latency hides under scan ----
    const int g0 = wv * GPW;
    float4 wr[GPW];
    if (WT) {
        const float4* w4 = (const float4*)Wv;
        #pragma unroll
        for (int q = 0; q < GPW; ++q)
            wr[q] = w4[(g0 + q) * COUT + lane];   // coalesced 1KB/instr, L2
    } else {
        #pragma unroll
        for (int q = 0; q < GPW; ++q) {
            const int xj = 4 * (g0 + q);
            wr[q].x = Wv[((xj + 0) >> 6) * 4096 + lane * 64 + ((xj + 0) & 63)];
            wr[q].y = Wv[((xj + 1) >> 6) * 4096 + lane * 64 + ((xj + 1) & 63)];
            wr[q].z = Wv[((xj + 2) >> 6) * 4096 + lane * 64 + ((xj + 2) & 63)];
            wr[q].w = Wv[((xj + 3) >> 6) * 4096 + lane * 64 + ((xj + 3) & 63)];
        }
    }

    // ---- stage geometry (coalesced float4) ----
    {
        const float4* src = (const float4*)(geom + (size_t)z * NPTS * 3);
        float4* dst = (float4*)smem;
        for (int k = threadIdx.x; k < NPTS * 3 / 4; k += BS)
            dst[k] = src[k];
    }
    __syncthreads();

    const float* geo = smem;
    const float gax = geo[a * 3 + 0];
    const float gay = geo[a * 3 + 1];
    const float gaz = geo[a * 3 + 2];
    const float* fz = feat + (size_t)z * NPTS * CIN;

    // ---- scan: 16 ballot steps; masks live in SGPRs (wave-uniform) ----
    unsigned long long masks[NSTEP];
    #pragma unroll
    for (int ss = 0; ss < NSTEP; ++ss) {
        const int b = ss * 64 + lane;
        float d2;
        {
            // Bit-exact vs numpy near boundary: no contraction, left-assoc.
            #pragma clang fp contract(off)
            const float dx = geo[b * 3 + 0] - gax;   // stride-3: conflict-free
            const float dy = geo[b * 3 + 1] - gay;
            const float dz = geo[b * 3 + 2] - gaz;
            d2 = dx * dx + dy * dy + dz * dz;
        }
        masks[ss] = __ballot(d2 < 0.25f);
    }

    // ---- process: walk masks with scalar ffsll; loads fully pipelined ----
    float acc0 = 0.f, acc1 = 0.f, acc2 = 0.f;
    #pragma unroll
    for (int ss = 0; ss < NSTEP; ++ss) {
        unsigned long long mm = masks[ss];
        while (mm) {                       // wave-uniform scalar loop
            const int src = __ffsll(mm) - 1;
            mm &= mm - 1ull;
            const int b = ss * 64 + src;   // wave-uniform
            const float gbx = geo[b * 3 + 0];   // uniform addr -> broadcast
            const float gby = geo[b * 3 + 1];
            const float gbz = geo[b * 3 + 2];
            const float dx = gbx - gax;    // bit-identical to scan's diff
            const float dy = gby - gay;
            const float dz = gbz - gaz;
            const float f = fz[(size_t)b * CIN + lane];  // coalesced 256B
            acc0 = fmaf(dx, f, acc0);
            acc1 = fmaf(dy, f, acc1);
            acc2 = fmaf(dz, f, acc2);
        }
    }

    float* tmp = smem + SM_TMP + wv * NXJ;
    tmp[0 * CIN + lane] = acc0;
    tmp[1 * CIN + lane] = acc1;
    tmp[2 * CIN + lane] = acc2;
    __syncthreads();   // geo dead after this; red region becomes live

    // ---- epilogue: wave wv owns W groups [6wv,6wv+6), all 8 points ----
    float* red = smem + SM_RED;   // red[wv*8+pp][i]
    #pragma unroll
    for (int pp = 0; pp < PPB; ++pp) {
        const float4* t4 = (const float4*)(smem + SM_TMP + pp * NXJ);
        f32x2 facc = {0.f, 0.f};
        #pragma unroll
        for (int q = 0; q < GPW; ++q) {
            const float4 t = t4[g0 + q];          // uniform -> LDS broadcast
            f32x2 ta; ta.x = t.x; ta.y = t.y;
            f32x2 tb; tb.x = t.z; tb.y = t.w;
            f32x2 wa; wa.x = wr[q].x; wa.y = wr[q].y;
            f32x2 wb; wb.x = wr[q].z; wb.y = wr[q].w;
            facc = ta * wa + facc;                // v_pk_fma_f32
            facc = tb * wb + facc;
        }
        red[(wv * PPB + pp) * COUT + lane] = facc.x + facc.y;
    }
    __syncthreads();

    float o = 0.f;
    #pragma unroll
    for (int w = 0; w < PPB; ++w)
        o += red[(w * PPB + wv) * COUT + lane];   // 2 lanes/bank: free

    out[(size_t)p * COUT + lane] = o;
}

extern "C" void kernel_launch(void* const* d_in, const int* in_sizes, int n_in,
                              void* d_out, int out_size, void* d_ws, size_t ws_size,
                              hipStream_t stream) {
    const float* feat = (const float*)d_in[0];  // [8,1024,64]
    const float* geom = (const float*)d_in[1];  // [8,1024,3]
    const float* W    = (const float*)d_in[2];  // [3,64,64]
    float* out        = (float*)d_out;          // [8,1024,64]

    const int nblocks = BATCHSZ * NPTS / PPB;   // 1024 blocks x 512 threads

    if (ws_size >= (size_t)(3 * COUT * CIN) * sizeof(float)) {
        float* Wt = (float*)d_ws;
        transpose_W_kernel<<<(3 * COUT * CIN + 255) / 256, 256, 0, stream>>>(W, Wt);
        neigh_conv_kernel<true><<<nblocks, BS, 0, stream>>>(feat, geom, Wt, out);
    } else {
        neigh_conv_kernel<false><<<nblocks, BS, 0, stream>>>(feat, geom, W, out);
    }
}